// Round 3
// baseline (254.599 us; speedup 1.0000x reference)
//
#include <hip/hip_runtime.h>
#include <hip/hip_bf16.h>
#include <hip/hip_fp16.h>

// Problem constants (match reference)
#define B_     8
#define L_     4096
#define DIN    256
#define DOUT   256
#define NGATE  1536   // 3*DOUT*2 dirs
#define KDIM   768    // 3*DIN (im2col window)
#define LP     (L_ + 2)
#define CHUNK  32
#define NCHUNK (L_ / CHUNK)
#define NKSTEP (KDIM / 64)   // 12 K-steps of BK=64

typedef short    short8  __attribute__((ext_vector_type(8)));
typedef __bf16   bf16x8  __attribute__((ext_vector_type(8)));
typedef float    floatx4 __attribute__((ext_vector_type(4)));
typedef _Float16 half4   __attribute__((ext_vector_type(4)));

__device__ __forceinline__ float fast_sigmoid(float x) {
    return __builtin_amdgcn_rcpf(1.f + __expf(-x));
}
__device__ __forceinline__ float fast_tanh(float x) {
    return 1.f - 2.f * __builtin_amdgcn_rcpf(1.f + __expf(2.f * x));
}
__device__ __forceinline__ unsigned short f2bf(float x) {
    unsigned u = __float_as_uint(x);
    u += 0x7FFF + ((u >> 16) & 1);   // RNE
    return (unsigned short)(u >> 16);
}
// Async global->LDS, 16B per lane. LDS dest = wave-uniform base + lane*16.
__device__ __forceinline__ void gload16(const unsigned short* g, unsigned short* l) {
    __builtin_amdgcn_global_load_lds((const __attribute__((address_space(1))) void*)g,
                                     (__attribute__((address_space(3))) void*)l,
                                     16, 0, 0);
}

// Native-layout gates addressing ------------------------------------------
// 256x256-tile 8-wave (2M x 4N) MFMA C-layout, fp16 flat unit index:
//   idx = (bm*6 + nblk)*65536 + (wr*4+wcl)*8192 + (ni*8+mi)*256
//       + (quad*16 + l16)*4 + rr
// For batch b, time t, gate column n (n in [0,1536)):
//   bm = b*16 + (t>>8); tt = t&255: mh=tt>>7, wr=(tt>>6)&1, mlo=(tt>>4)&3,
//   quad=(tt>>2)&3, rr=t&3; mi = mh*4+mlo
//   nblk = n>>8; nn = n&255: nh=nn>>7, wcl=(nn>>5)&3, nlo=(nn>>4)&1, l16=n&15;
//   ni = nh*2+nlo
// rr has stride 1, so half4 loads over 4 consecutive t still work.
__device__ __forceinline__ int gate_noff(int n) {
    return (n >> 8) * 65536 + ((n >> 5) & 3) * 8192
         + (((n >> 7) & 1) * 2 + ((n >> 4) & 1)) * 2048 + (n & 15) * 4;
}
__device__ __forceinline__ int gate_toff(int b, int t) {
    return (b * 16 + (t >> 8)) * 393216 + ((t >> 6) & 1) * 32768
         + (((t >> 7) & 1) * 4 + ((t >> 4) & 3)) * 256 + ((t >> 2) & 3) * 64;
}

// ---------------------------------------------------------------------------
// prep_all: fused prep_x (blocks [0,NXB)) + prep_w (blocks [NXB,..)).
#define NXB ((B_ * LP * 64 + 255) / 256)
#define NWB ((NGATE * KDIM + 255) / 256)
__global__ void prep_all(const float* __restrict__ x, unsigned short* __restrict__ Xp,
                         const float* __restrict__ Wf, const float* __restrict__ bf_,
                         const float* __restrict__ Wb, const float* __restrict__ bb,
                         unsigned short* __restrict__ Wc, float* __restrict__ bc) {
    if (blockIdx.x < NXB) {
        int idx = blockIdx.x * 256 + threadIdx.x;
        int row = idx >> 6;
        if (row >= B_ * LP) return;
        int c4 = (idx & 63) << 2;
        int b = row / LP, r = row - b * LP;
        float4 v = make_float4(0.f, 0.f, 0.f, 0.f);
        if (r >= 1 && r <= L_) {
            v = *(const float4*)(x + ((size_t)(b * L_ + (r - 1))) * DIN + c4);
        }
        ushort4 o = make_ushort4(f2bf(v.x), f2bf(v.y), f2bf(v.z), f2bf(v.w));
        *(ushort4*)(Xp + (size_t)row * DIN + c4) = o;
    } else {
        int gid = (blockIdx.x - NXB) * 256 + threadIdx.x;
        if (gid < NGATE) {
            bc[gid] = (gid < 768) ? bf_[gid] : bb[gid - 768];
        }
        if (gid >= NGATE * KDIM) return;
        int n = gid / KDIM, k = gid - n * KDIM;
        int s = k >> 8, ic = k & 255;
        const float* W = (n < 768) ? Wf : Wb;
        int oc = (n < 768) ? n : n - 768;
        float v = W[(size_t)oc * KDIM + ic * 3 + s];
        Wc[(size_t)n * KDIM + k] = f2bf(v);
    }
}

// ---------------------------------------------------------------------------
// gemm_gates: 256x256 tile, 512 threads (8 waves = 2M x 4N), BK=64,
// 16x16x32 bf16 MFMA. 4 phases per K-step with READ-AHEAD register
// fragments: phase p issues the ds_reads for phase p+1's fragments, then
// waits a COUNTED lgkmcnt(N) (N = reads issued this phase; DS completes
// in-order) so the MFMA cluster only depends on reads issued a full phase
// earlier. DS bursts overlap MFMA instead of serializing in front of it.
// Per-phase reads: p1=4 (B1), p2=8 (A1), p3=8 (A0 of k+1 from nb),
// p4=4 (B0 of k+1 from nb) = 24/wave/K-step.
// Fragment registers recycled: each read-ahead targets a set whose last
// MFMA consumer already issued (in-order per wave => WAR safe).
// Staging (unchanged): p1 A1(k+1)->nb, p2 B1(k+1)->nb, p3 B0(k+2)->cb,
// p4 A0(k+2)->cb. vmcnt(4) at p2-end (BEFORE the barrier, so other waves'
// A0/B0(k+1) stages are published to LDS before p3/p4 read them) and at
// window end (drains A1/B1(k+1) before next window's p1/p2 reads).
// Overwrite safety: each LDS half's reads are drained by a counted lgkm
// >=2 phases (>=2 barriers) before the stage that overwrites it.
__launch_bounds__(512, 2)
__global__ void gemm_gates(const unsigned short* __restrict__ Xp,
                           const unsigned short* __restrict__ Wc,
                           const float* __restrict__ bc,
                           _Float16* __restrict__ gates) {
    __shared__ alignas(16) unsigned short As[2][16384];   // 64 KB
    __shared__ alignas(16) unsigned short Bs[2][16384];   // 64 KB
    const int tid  = threadIdx.x;
    const int lane = tid & 63, w = tid >> 6;        // wave 0..7
    const int quad = lane >> 4, l16 = lane & 15;
    const int wr = w >> 2, wcl = w & 3;             // wr 0..1 (m), wcl 0..3 (n)

    int flat = blockIdx.x;                 // 0..767
    int xcd  = flat & 7;
    int slot = flat >> 3;                  // 0..95
    int bm   = xcd * 16 + slot / 6;        // 0..127 m-tile (256 rows each)
    int nblk = slot % 6;                   // 0..5   n-tile (256 cols each)
    const int b  = bm >> 4;
    const int t0 = (bm & 15) << 8;
    const int n0 = nblk << 8;
    const unsigned short* Ab = Xp + (size_t)b * LP * DIN;

    // Per-lane inverse-swizzle source mapping for one 128x64 half-tile
    // (identical for A and B halves; constant across K-steps).
    int rS[2], cgS[2];
#pragma unroll
    for (int j = 0; j < 2; j++) {
        int G = (j * 8 + w) * 64 + lane;         // granule 0..1023
        rS[j]  = G >> 3;                         // local row 0..127
        cgS[j] = ((G & 7) ^ (rS[j] & 7)) * 8;    // swizzled column (shorts)
    }

    floatx4 acc[8][4];
#pragma unroll
    for (int i = 0; i < 8; i++)
#pragma unroll
        for (int j = 0; j < 4; j++) acc[i][j] = (floatx4)0.f;

#define STAGE_A(ks, mh, cb) do {                                               \
    const int sh_ = (ks) >> 2, c0_ = ((ks) & 3) * 64;                          \
    _Pragma("unroll")                                                          \
    for (int j_ = 0; j_ < 2; ++j_)                                             \
        gload16(Ab + (size_t)(t0 + (mh) * 128 + rS[j_] + sh_) * DIN + c0_ + cgS[j_], \
                &As[cb][(mh) * 8192 + (j_ * 8 + w) * 512]);                    \
} while (0)

#define STAGE_B(ks, nh, cb) do {                                               \
    const int k0_ = (ks) * 64;                                                 \
    _Pragma("unroll")                                                          \
    for (int j_ = 0; j_ < 2; ++j_)                                             \
        gload16(Wc + (size_t)(n0 + (nh) * 128 + rS[j_]) * KDIM + k0_ + cgS[j_], \
                &Bs[cb][(nh) * 8192 + (j_ * 8 + w) * 512]);                    \
} while (0)

#define DSREAD_A(dst, mh, cb) do {                                             \
    _Pragma("unroll")                                                          \
    for (int m_ = 0; m_ < 4; ++m_) {                                           \
        const int R = (mh) * 128 + wr * 64 + m_ * 16 + l16;                    \
        const int rx = R & 7;                                                  \
        dst[m_][0] = *(const short8*)&As[cb][R * 64 + ((quad ^ rx) << 3)];     \
        dst[m_][1] = *(const short8*)&As[cb][R * 64 + (((4 + quad) ^ rx) << 3)]; \
    }                                                                          \
} while (0)

#define DSREAD_B(dst, nh, cb) do {                                             \
    _Pragma("unroll")                                                          \
    for (int n_ = 0; n_ < 2; ++n_) {                                           \
        const int R = (nh) * 128 + wcl * 32 + n_ * 16 + l16;                   \
        const int rx = R & 7;                                                  \
        dst[n_][0] = *(const short8*)&Bs[cb][R * 64 + ((quad ^ rx) << 3)];     \
        dst[n_][1] = *(const short8*)&Bs[cb][R * 64 + (((4 + quad) ^ rx) << 3)]; \
    }                                                                          \
} while (0)

#define MFMA16(ah, bh, mh, nh)                                                 \
    _Pragma("unroll")                                                          \
    for (int m_ = 0; m_ < 4; ++m_)                                             \
    _Pragma("unroll")                                                          \
    for (int n_ = 0; n_ < 2; ++n_) {                                           \
        acc[(mh)*4 + m_][(nh)*2 + n_] = __builtin_amdgcn_mfma_f32_16x16x32_bf16( \
            __builtin_bit_cast(bf16x8, ah[m_][0]),                             \
            __builtin_bit_cast(bf16x8, bh[n_][0]),                             \
            acc[(mh)*4 + m_][(nh)*2 + n_], 0, 0, 0);                           \
        acc[(mh)*4 + m_][(nh)*2 + n_] = __builtin_amdgcn_mfma_f32_16x16x32_bf16( \
            __builtin_bit_cast(bf16x8, ah[m_][1]),                             \
            __builtin_bit_cast(bf16x8, bh[n_][1]),                             \
            acc[(mh)*4 + m_][(nh)*2 + n_], 0, 0, 0);                           \
    }

    // Fragment register sets live across windows (read-ahead recycling).
    short8 a0[4][2], a1[4][2], b0[2][2], b1[2][2];

#define WINDOW(kv, cb, nb) do {                                                \
    const int k_ = (kv);                                                       \
    /* p1: read B1(cb)->b1 (next phase); stage A1(k+1)->nb */                  \
    DSREAD_B(b1, 1, cb);                                                       \
    if (k_ + 1 < NKSTEP) STAGE_A(k_ + 1, 1, nb);                               \
    __builtin_amdgcn_s_barrier();                                              \
    asm volatile("s_waitcnt lgkmcnt(4)" ::: "memory");                         \
    __builtin_amdgcn_s_setprio(1); MFMA16(a0, b0, 0, 0);                       \
    __builtin_amdgcn_s_setprio(0);                                             \
    __builtin_amdgcn_s_barrier();                                              \
    /* p2: read A1(cb)->a1; stage B1(k+1)->nb; pre-drain A0/B0(k+1) stages */  \
    DSREAD_A(a1, 1, cb);                                                       \
    if (k_ + 1 < NKSTEP) STAGE_B(k_ + 1, 1, nb);                               \
    __builtin_amdgcn_s_barrier();                                              \
    asm volatile("s_waitcnt lgkmcnt(7)" ::: "memory");                         \
    __builtin_amdgcn_s_setprio(1); MFMA16(a0, b1, 0, 1);                       \
    __builtin_amdgcn_s_setprio(0);                                             \
    if (k_ + 1 < NKSTEP) { asm volatile("s_waitcnt vmcnt(4)" ::: "memory"); }  \
    __builtin_amdgcn_s_barrier();                                              \
    /* p3: read A0(k+1)(nb)->a0; stage B0(k+2)->cb */                          \
    if (k_ + 1 < NKSTEP) DSREAD_A(a0, 0, nb);                                  \
    if (k_ + 2 < NKSTEP) STAGE_B(k_ + 2, 0, cb);                               \
    __builtin_amdgcn_s_barrier();                                              \
    if (k_ + 1 < NKSTEP) { asm volatile("s_waitcnt lgkmcnt(8)" ::: "memory"); }\
    else                 { asm volatile("s_waitcnt lgkmcnt(0)" ::: "memory"); }\
    __builtin_amdgcn_s_setprio(1); MFMA16(a1, b0, 1, 0);                       \
    __builtin_amdgcn_s_setprio(0);                                             \
    __builtin_amdgcn_s_barrier();                                              \
    /* p4: read B0(k+1)(nb)->b0; stage A0(k+2)->cb */                          \
    if (k_ + 1 < NKSTEP) DSREAD_B(b0, 0, nb);                                  \
    if (k_ + 2 < NKSTEP) STAGE_A(k_ + 2, 0, cb);                               \
    __builtin_amdgcn_s_barrier();                                              \
    if (k_ + 1 < NKSTEP) { asm volatile("s_waitcnt lgkmcnt(11)" ::: "memory"); }\
    else                 { asm volatile("s_waitcnt lgkmcnt(0)" ::: "memory"); }\
    __builtin_amdgcn_s_setprio(1); MFMA16(a1, b1, 1, 1);                       \
    __builtin_amdgcn_s_setprio(0);                                             \
    if (k_ + 2 < NKSTEP) { asm volatile("s_waitcnt vmcnt(4)" ::: "memory"); }  \
    else                 { asm volatile("s_waitcnt vmcnt(0)" ::: "memory"); }  \
    __builtin_amdgcn_s_barrier();                                              \
} while (0)

    // Prologue: K-step 0 (4 halves) + A0/B0 of K-step 1; drain K-step 0
    // (vmcnt(4) leaves the two K1 halves in flight), then pre-read the
    // first fragment sets a0,b0 so window 0's p1 MFMA is read-ahead fed.
    STAGE_A(0, 0, 0); STAGE_B(0, 0, 0); STAGE_A(0, 1, 0); STAGE_B(0, 1, 0);
    STAGE_A(1, 0, 1); STAGE_B(1, 0, 1);
    asm volatile("s_waitcnt vmcnt(4)" ::: "memory");
    __builtin_amdgcn_s_barrier();
    DSREAD_A(a0, 0, 0); DSREAD_B(b0, 0, 0);

    for (int kp = 0; kp < NKSTEP / 2; ++kp) {
        WINDOW(2 * kp,     0, 1);
        WINDOW(2 * kp + 1, 1, 0);
    }

#undef WINDOW
#undef MFMA16
#undef DSREAD_B
#undef DSREAD_A
#undef STAGE_B
#undef STAGE_A

    // Epilogue: bias + activation, native-layout 8B stores (512B/wave/instr).
    const int cls = nblk % 3;                      // 0=f,1=o,2=z (wave-uniform)
    _Float16* gb = gates + ((size_t)((bm * 6 + nblk) * 8 + w)) * 8192 + lane * 4;
#pragma unroll
    for (int ni = 0; ni < 4; ++ni) {
        const float bias = bc[n0 + (ni >> 1) * 128 + wcl * 32 + (ni & 1) * 16 + l16];
#pragma unroll
        for (int mi = 0; mi < 8; ++mi) {
            half4 hv;
#pragma unroll
            for (int rr = 0; rr < 4; ++rr) {
                float v = acc[mi][ni][rr] + bias;
                v = (cls == 2) ? fast_tanh(v) : fast_sigmoid(v);
                hv[rr] = (_Float16)v;
            }
            *(half4*)(gb + (ni * 8 + mi) * 256) = hv;
        }
    }
}

// ---------------------------------------------------------------------------
// scan_chunks (phase A): thread = one channel, block = one (chunk,b,dir).
// Reads f,z in native layout (8B = 4 consecutive t per load), composes the
// chunk affine map c_out = P*c_in + W.
__global__ void scan_chunks(const _Float16* __restrict__ gates,
                            float2* __restrict__ PW) {
    const int d = threadIdx.x;                       // channel 0..255
    const int s = blockIdx.x, b = blockIdx.y, dir = blockIdx.z;
    const int onf = gate_noff(dir * 768 + d);
    const int onz = gate_noff(dir * 768 + 512 + d);
    float P = 1.f, W = 0.f;
    if (dir == 0) {
#pragma unroll
        for (int gi = 0; gi < 8; gi++) {
            int t = s * CHUNK + gi * 4;
            int ot = gate_toff(b, t);
            half4 f4 = *(const half4*)(gates + ot + onf);
            half4 z4 = *(const half4*)(gates + ot + onz);
#pragma unroll
            for (int u = 0; u < 4; u++) {
                float f = (float)f4[u], z = (float)z4[u];
                W = f * W + (1.f - f) * z;
                P *= f;
            }
        }
    } else {
#pragma unroll
        for (int gi = 7; gi >= 0; gi--) {
            int t = s * CHUNK + gi * 4;
            int ot = gate_toff(b, t);
            half4 f4 = *(const half4*)(gates + ot + onf);
            half4 z4 = *(const half4*)(gates + ot + onz);
#pragma unroll
            for (int u = 3; u >= 0; u--) {
                float f = (float)f4[u], z = (float)z4[u];
                W = f * W + (1.f - f) * z;
                P *= f;
            }
        }
    }
    PW[(((size_t)(dir * 8 + b)) * NCHUNK + s) * 256 + d] = make_float2(P, W);
}

// ---------------------------------------------------------------------------
// scan_seq (phase B): sequential scan over NCHUNK=128 chunks.
__global__ void scan_seq(const float2* __restrict__ PW, float* __restrict__ C0) {
    const int c = threadIdx.x;
    const int dir = blockIdx.x >> 3, b = blockIdx.x & 7;
    const size_t base = ((size_t)(dir * 8 + b)) * NCHUNK * 256 + c;
    float cc = 0.f;
    if (dir == 0) {
#pragma unroll 16
        for (int s = 0; s < NCHUNK; s++) {
            float2 pw = PW[base + (size_t)s * 256];
            C0[base + (size_t)s * 256] = cc;
            cc = pw.x * cc + pw.y;
        }
    } else {
#pragma unroll 16
        for (int s = NCHUNK - 1; s >= 0; s--) {
            float2 pw = PW[base + (size_t)s * 256];
            C0[base + (size_t)s * 256] = cc;
            cc = pw.x * cc + pw.y;
        }
    }
}

// ---------------------------------------------------------------------------
// scan_final (phase C): thread = one channel, block = one (chunk,b,dir).
// Replays the chunk from C0; h values round-trip through a 4KB LDS tile per
// 4-t group so the global store is [t][ch]-contiguous float4 per lane.
__global__ void scan_final(const _Float16* __restrict__ gates,
                           const float* __restrict__ C0,
                           float* __restrict__ out) {
    __shared__ float hbuf[4][256];
    const int d = threadIdx.x;
    const int s = blockIdx.x, b = blockIdx.y, dir = blockIdx.z;
    const int onf = gate_noff(dir * 768 + d);
    const int ono = gate_noff(dir * 768 + 256 + d);
    const int onz = gate_noff(dir * 768 + 512 + d);
    float c = C0[(((size_t)(dir * 8 + b)) * NCHUNK + s) * 256 + d];
    float* ob = out + (size_t)(b * L_) * (2 * DOUT) + dir * DOUT;
    float* lasth = out + (size_t)B_ * L_ * (2 * DOUT);
    float* lastc = lasth + B_ * (2 * DOUT);
    const int tl = d >> 6, cl = (d & 63) * 4;    // output-store mapping

    for (int gg = 0; gg < 8; gg++) {
        int gi = (dir == 0) ? gg : 7 - gg;
        int t = s * CHUNK + gi * 4;
        int ot = gate_toff(b, t);
        half4 f4 = *(const half4*)(gates + ot + onf);
        half4 o4 = *(const half4*)(gates + ot + ono);
        half4 z4 = *(const half4*)(gates + ot + onz);
        float h[4];
        if (dir == 0) {
#pragma unroll
            for (int u = 0; u < 4; u++) {
                float f = (float)f4[u], z = (float)z4[u];
                c = f * c + (1.f - f) * z;
                h[u] = c * (float)o4[u];
            }
            if (s == NCHUNK - 1 && gi == 7) {
                lasth[b * 2 * DOUT + d] = h[3];
                lastc[b * 2 * DOUT + d] = c;
            }
        } else {
#pragma unroll
            for (int u = 3; u >= 0; u--) {
                float f = (float)f4[u], z = (float)z4[u];
                c = f * c + (1.f - f) * z;
                h[u] = c * (float)o4[u];
                if (u == 3 && s == NCHUNK - 1 && gi == 7) {
                    lasth[b * 2 * DOUT + DOUT + d] = h[3];
                    lastc[b * 2 * DOUT + DOUT + d] = c;
                }
            }
        }
        hbuf[0][d] = h[0];
        hbuf[1][d] = h[1];
        hbuf[2][d] = h[2];
        hbuf[3][d] = h[3];
        __syncthreads();
        *(float4*)&ob[(size_t)(t + tl) * (2 * DOUT) + cl] = *(float4*)&hbuf[tl][cl];
        __syncthreads();
    }
}

// ---------------------------------------------------------------------------
extern "C" void kernel_launch(void* const* d_in, const int* in_sizes, int n_in,
                              void* d_out, int out_size, void* d_ws, size_t ws_size,
                              hipStream_t stream) {
    const float* x   = (const float*)d_in[0];
    // d_in[1] = lengths (unused by the reference computation)
    const float* Wf  = (const float*)d_in[2];
    const float* bfv = (const float*)d_in[3];
    const float* Wb  = (const float*)d_in[4];
    const float* bbv = (const float*)d_in[5];

    char* ws = (char*)d_ws;
    // Workspace layout (bytes):
    //   Xp    bf16  B*(L+2)*256          = 16,785,408   (offset 0; dead after GEMM)
    //   Wc    bf16  1536*768             =  2,359,296   (offset 16,785,408)
    //   bc    f32   1536                 =      6,144   (offset 19,144,704)
    //   gates fp16  B*L*1536             = 100,663,296  (offset 19,150,848, native layout)
    //   PW    f32x2 2*8*128*256          =  4,194,304   (offset 0 — reuses Xp)
    //   C0    f32   2*8*128*256          =  2,097,152   (offset 4,194,304 — reuses Xp)
    unsigned short* Xp    = (unsigned short*)(ws);
    unsigned short* Wc    = (unsigned short*)(ws + 16785408);
    float*          bc    = (float*)(ws + 19144704);
    _Float16*       gates = (_Float16*)(ws + 19150848);
    float2*         PW    = (float2*)(ws);              // reuse Xp region
    float*          C0    = (float*)(ws + 4194304);     // reuse Xp region
    float*          out   = (float*)d_out;

    prep_all<<<NXB + NWB, 256, 0, stream>>>(x, Xp, Wf, bfv, Wb, bbv, Wc, bc);
    gemm_gates<<<768, 512, 0, stream>>>(Xp, Wc, bc, gates);
    scan_chunks<<<dim3(NCHUNK, B_, 2), 256, 0, stream>>>(gates, PW);
    scan_seq<<<16, 256, 0, stream>>>(PW, C0);
    scan_final<<<dim3(NCHUNK, B_, 2), 256, 0, stream>>>(gates, C0, out);
}

// Round 4
// 221.589 us; speedup vs baseline: 1.1490x; 1.1490x over previous
//
#include <hip/hip_runtime.h>
#include <hip/hip_bf16.h>
#include <hip/hip_fp16.h>

// Problem constants (match reference)
#define B_     8
#define L_     4096
#define DIN    256
#define DOUT   256
#define NGATE  1536   // 3*DOUT*2 dirs
#define KDIM   768    // 3*DIN (im2col window)
#define LP     (L_ + 2)
#define CHUNK  32
#define NCHUNK (L_ / CHUNK)

typedef short    short8  __attribute__((ext_vector_type(8)));
typedef __bf16   bf16x8  __attribute__((ext_vector_type(8)));
typedef float    floatx4 __attribute__((ext_vector_type(4)));
typedef _Float16 half4   __attribute__((ext_vector_type(4)));

__device__ __forceinline__ float fast_sigmoid(float x) {
    return __builtin_amdgcn_rcpf(1.f + __expf(-x));
}
__device__ __forceinline__ float fast_tanh(float x) {
    return 1.f - 2.f * __builtin_amdgcn_rcpf(1.f + __expf(2.f * x));
}
__device__ __forceinline__ unsigned short f2bf(float x) {
    unsigned u = __float_as_uint(x);
    u += 0x7FFF + ((u >> 16) & 1);   // RNE
    return (unsigned short)(u >> 16);
}
// Async global->LDS, 16B per lane. LDS dest = wave-uniform base + lane*16.
__device__ __forceinline__ void gload16(const unsigned short* g, unsigned short* l) {
    __builtin_amdgcn_global_load_lds((const __attribute__((address_space(1))) void*)g,
                                     (__attribute__((address_space(3))) void*)l,
                                     16, 0, 0);
}

// Native-layout gates addressing ------------------------------------------
// gates fp16, flat unit index:
//   A(t,n) = ((bm*12 + nblk)*8 + (wr*2+wcl))*4096 + (ni*4+mi)*256
//            + (quad*16 + l16)*4 + rr
// where (for batch b, time t, gate column n):
//   bm = b*16 + (t>>8), wr = (t>>6)&3, mi = (t>>4)&3, quad = (t>>2)&3, rr = t&3
//   nblk = n>>7, wcl = (n>>6)&1, ni = (n>>4)&3, l16 = n&15
// This is exactly the MFMA C-layout of gemm_gates, so the epilogue stores a
// lane's 4 accumulators (4 consecutive t, one n) as one contiguous 8B chunk.
__device__ __forceinline__ int gate_noff(int n) {
    return (n >> 7) * 32768 + ((n >> 6) & 1) * 4096 + ((n >> 4) & 3) * 1024 + (n & 15) * 4;
}
__device__ __forceinline__ int gate_toff(int b, int t) {
    return (b * 16 + (t >> 8)) * 393216 + ((t >> 6) & 3) * 8192
         + ((t >> 4) & 3) * 256 + ((t >> 2) & 3) * 64;
}

// ---------------------------------------------------------------------------
// prep_all: fused prep_x (blocks [0,NXB)) + prep_w (blocks [NXB,..)).
#define NXB ((B_ * LP * 64 + 255) / 256)
#define NWB ((NGATE * KDIM + 255) / 256)
__global__ void prep_all(const float* __restrict__ x, unsigned short* __restrict__ Xp,
                         const float* __restrict__ Wf, const float* __restrict__ bf_,
                         const float* __restrict__ Wb, const float* __restrict__ bb,
                         unsigned short* __restrict__ Wc, float* __restrict__ bc) {
    if (blockIdx.x < NXB) {
        int idx = blockIdx.x * 256 + threadIdx.x;
        int row = idx >> 6;
        if (row >= B_ * LP) return;
        int c4 = (idx & 63) << 2;
        int b = row / LP, r = row - b * LP;
        float4 v = make_float4(0.f, 0.f, 0.f, 0.f);
        if (r >= 1 && r <= L_) {
            v = *(const float4*)(x + ((size_t)(b * L_ + (r - 1))) * DIN + c4);
        }
        ushort4 o = make_ushort4(f2bf(v.x), f2bf(v.y), f2bf(v.z), f2bf(v.w));
        *(ushort4*)(Xp + (size_t)row * DIN + c4) = o;
    } else {
        int gid = (blockIdx.x - NXB) * 256 + threadIdx.x;
        if (gid < NGATE) {
            bc[gid] = (gid < 768) ? bf_[gid] : bb[gid - 768];
        }
        if (gid >= NGATE * KDIM) return;
        int n = gid / KDIM, k = gid - n * KDIM;
        int s = k >> 8, ic = k & 255;
        const float* W = (n < 768) ? Wf : Wb;
        int oc = (n < 768) ? n : n - 768;
        float v = W[(size_t)oc * KDIM + ic * 3 + s];
        Wc[(size_t)n * KDIM + k] = f2bf(v);
    }
}

// ---------------------------------------------------------------------------
// gemm_gates: 256x128 tile, 512 threads (8 waves), BK=64, 16x16x32 bf16 MFMA.
// global_load_lds staging with source-side XOR swizzle. Epilogue stores in
// MFMA-native layout: one 8B store per (ni,mi) per lane -> 512B contiguous
// per instruction, full-line writes. (Round-0 proven version: 2-barrier
// structure at its ~36% structural ceiling, 3 blocks/CU inter-block overlap;
// rounds 1-3 showed 8-phase ports regress on this short-K shape.)
__launch_bounds__(512)
__global__ void gemm_gates(const unsigned short* __restrict__ Xp,
                           const unsigned short* __restrict__ Wc,
                           const float* __restrict__ bc,
                           _Float16* __restrict__ gates) {
    __shared__ unsigned short As[256 * 64];   // 32 KB
    __shared__ unsigned short Bs[128 * 64];   // 16 KB
    const int tid  = threadIdx.x;
    const int lane = tid & 63, wave = tid >> 6;     // wave 0..7
    const int quad = lane >> 4, l16 = lane & 15;
    const int wr = wave >> 1, wcl = wave & 1;       // wr 0..3 (m), wcl 0..1 (n)

    int flat = blockIdx.x;                 // 0..1535
    int xcd  = flat & 7;
    int slot = flat >> 3;                  // 0..191
    int bm   = xcd * 16 + slot / 12;       // 0..127 m-tile (256 rows each)
    int nblk = slot % 12;
    const int b  = bm >> 4;
    const int t0 = (bm & 15) << 8;
    const int n0 = nblk << 7;
    const unsigned short* Ab = Xp + (size_t)b * LP * DIN;

    // Per-lane inverse-swizzle source mapping (constant across k-steps).
    int rowA[4], cgA[4], rowB[2], cgB[2];
#pragma unroll
    for (int j = 0; j < 4; j++) {
        int G = (wave * 4 + j) * 64 + lane;      // A granule 0..2047
        rowA[j] = G >> 3;
        cgA[j]  = ((G & 7) ^ (rowA[j] & 7)) * 8;
    }
#pragma unroll
    for (int j = 0; j < 2; j++) {
        int G = (wave * 2 + j) * 64 + lane;      // B granule 0..1023
        rowB[j] = G >> 3;
        cgB[j]  = ((G & 7) ^ (rowB[j] & 7)) * 8;
    }

    floatx4 acc[4][4];
#pragma unroll
    for (int i = 0; i < 4; i++)
#pragma unroll
        for (int j = 0; j < 4; j++) acc[i][j] = (floatx4)0.f;

    for (int k0 = 0; k0 < KDIM; k0 += 64) {
        const int sh = k0 >> 8;        // time shift 0..2
        const int c0 = k0 & 255;       // column offset within DIN
#pragma unroll
        for (int j = 0; j < 4; j++)
            gload16(Ab + (size_t)(t0 + rowA[j] + sh) * DIN + c0 + cgA[j],
                    &As[(wave * 4 + j) * 512]);
#pragma unroll
        for (int j = 0; j < 2; j++)
            gload16(Wc + (size_t)(n0 + rowB[j]) * KDIM + k0 + cgB[j],
                    &Bs[(wave * 2 + j) * 512]);
        __syncthreads();
#pragma unroll
        for (int kk = 0; kk < 2; kk++) {
            const int g0 = kk * 4 + quad;
            short8 af[4], bfr[4];
#pragma unroll
            for (int mi = 0; mi < 4; mi++) {
                int row = wr * 64 + mi * 16 + l16;
                af[mi] = *(const short8*)&As[row * 64 + ((g0 ^ (row & 7)) << 3)];
            }
#pragma unroll
            for (int ni = 0; ni < 4; ni++) {
                int row = wcl * 64 + ni * 16 + l16;
                bfr[ni] = *(const short8*)&Bs[row * 64 + ((g0 ^ (row & 7)) << 3)];
            }
#pragma unroll
            for (int mi = 0; mi < 4; mi++)
#pragma unroll
                for (int ni = 0; ni < 4; ni++)
                    acc[mi][ni] = __builtin_amdgcn_mfma_f32_16x16x32_bf16(
                        __builtin_bit_cast(bf16x8, af[mi]),
                        __builtin_bit_cast(bf16x8, bfr[ni]),
                        acc[mi][ni], 0, 0, 0);
        }
        __syncthreads();
    }

    // Epilogue: bias + activation, native-layout 8B stores.
    const int cls = ((n0 + wcl * 64) >> 8) % 3;   // wave-uniform gate class
    _Float16* gb = gates + ((size_t)(bm * 12 + nblk) * 8 + wave) * 4096 + lane * 4;
#pragma unroll
    for (int ni = 0; ni < 4; ni++) {
        float bias = bc[n0 + wcl * 64 + ni * 16 + l16];
#pragma unroll
        for (int mi = 0; mi < 4; mi++) {
            half4 hv;
#pragma unroll
            for (int rr = 0; rr < 4; rr++) {
                float v = acc[mi][ni][rr] + bias;
                v = (cls == 2) ? fast_tanh(v) : fast_sigmoid(v);
                hv[rr] = (_Float16)v;
            }
            *(half4*)(gb + (ni * 4 + mi) * 256) = hv;
        }
    }
}

// ---------------------------------------------------------------------------
// scan_chunks (phase A): thread = one channel, block = one (chunk,b,dir).
// Reads f,z in native layout (8B = 4 consecutive t per load), composes the
// chunk affine map c_out = P*c_in + W.
__global__ void scan_chunks(const _Float16* __restrict__ gates,
                            float2* __restrict__ PW) {
    const int d = threadIdx.x;                       // channel 0..255
    const int s = blockIdx.x, b = blockIdx.y, dir = blockIdx.z;
    const int onf = gate_noff(dir * 768 + d);
    const int onz = gate_noff(dir * 768 + 512 + d);
    float P = 1.f, W = 0.f;
    if (dir == 0) {
#pragma unroll
        for (int gi = 0; gi < 8; gi++) {
            int t = s * CHUNK + gi * 4;
            int ot = gate_toff(b, t);
            half4 f4 = *(const half4*)(gates + ot + onf);
            half4 z4 = *(const half4*)(gates + ot + onz);
#pragma unroll
            for (int u = 0; u < 4; u++) {
                float f = (float)f4[u], z = (float)z4[u];
                W = f * W + (1.f - f) * z;
                P *= f;
            }
        }
    } else {
#pragma unroll
        for (int gi = 7; gi >= 0; gi--) {
            int t = s * CHUNK + gi * 4;
            int ot = gate_toff(b, t);
            half4 f4 = *(const half4*)(gates + ot + onf);
            half4 z4 = *(const half4*)(gates + ot + onz);
#pragma unroll
            for (int u = 3; u >= 0; u--) {
                float f = (float)f4[u], z = (float)z4[u];
                W = f * W + (1.f - f) * z;
                P *= f;
            }
        }
    }
    PW[(((size_t)(dir * 8 + b)) * NCHUNK + s) * 256 + d] = make_float2(P, W);
}

// ---------------------------------------------------------------------------
// scan_seq (phase B): sequential scan over NCHUNK=128 chunks.
__global__ void scan_seq(const float2* __restrict__ PW, float* __restrict__ C0) {
    const int c = threadIdx.x;
    const int dir = blockIdx.x >> 3, b = blockIdx.x & 7;
    const size_t base = ((size_t)(dir * 8 + b)) * NCHUNK * 256 + c;
    float cc = 0.f;
    if (dir == 0) {
#pragma unroll 16
        for (int s = 0; s < NCHUNK; s++) {
            float2 pw = PW[base + (size_t)s * 256];
            C0[base + (size_t)s * 256] = cc;
            cc = pw.x * cc + pw.y;
        }
    } else {
#pragma unroll 16
        for (int s = NCHUNK - 1; s >= 0; s--) {
            float2 pw = PW[base + (size_t)s * 256];
            C0[base + (size_t)s * 256] = cc;
            cc = pw.x * cc + pw.y;
        }
    }
}

// ---------------------------------------------------------------------------
// scan_final (phase C): thread = one channel, block = one (chunk,b,dir).
// Replays the chunk from C0. NEW: all 32 t x 256 ch of h accumulate into one
// 32KB LDS tile with a SINGLE barrier (was 16 barriers = 2 per 4-t group),
// so all 24 gates loads per thread can be in flight without barrier-imposed
// serialization; then 8 fully-coalesced float4 stores per thread
// (1KB/wave/instr, [t][ch]-contiguous).
__global__ void scan_final(const _Float16* __restrict__ gates,
                           const float* __restrict__ C0,
                           float* __restrict__ out) {
    __shared__ float hbuf[CHUNK][256];   // 32 KB
    const int d = threadIdx.x;
    const int s = blockIdx.x, b = blockIdx.y, dir = blockIdx.z;
    const int onf = gate_noff(dir * 768 + d);
    const int ono = gate_noff(dir * 768 + 256 + d);
    const int onz = gate_noff(dir * 768 + 512 + d);
    float c = C0[(((size_t)(dir * 8 + b)) * NCHUNK + s) * 256 + d];
    float* ob = out + (size_t)(b * L_) * (2 * DOUT) + dir * DOUT;
    float* lasth = out + (size_t)B_ * L_ * (2 * DOUT);
    float* lastc = lasth + B_ * (2 * DOUT);

#pragma unroll
    for (int gg = 0; gg < 8; gg++) {
        int gi = (dir == 0) ? gg : 7 - gg;
        int t = s * CHUNK + gi * 4;
        int ot = gate_toff(b, t);
        half4 f4 = *(const half4*)(gates + ot + onf);
        half4 o4 = *(const half4*)(gates + ot + ono);
        half4 z4 = *(const half4*)(gates + ot + onz);
        if (dir == 0) {
#pragma unroll
            for (int u = 0; u < 4; u++) {
                float f = (float)f4[u], z = (float)z4[u];
                c = f * c + (1.f - f) * z;
                float h = c * (float)o4[u];
                hbuf[gi * 4 + u][d] = h;
                if (s == NCHUNK - 1 && gi == 7 && u == 3) {
                    lasth[b * 2 * DOUT + d] = h;
                    lastc[b * 2 * DOUT + d] = c;
                }
            }
        } else {
#pragma unroll
            for (int u = 3; u >= 0; u--) {
                float f = (float)f4[u], z = (float)z4[u];
                c = f * c + (1.f - f) * z;
                float h = c * (float)o4[u];
                hbuf[gi * 4 + u][d] = h;
                if (u == 3 && s == NCHUNK - 1 && gi == 7) {
                    lasth[b * 2 * DOUT + DOUT + d] = h;
                    lastc[b * 2 * DOUT + DOUT + d] = c;
                }
            }
        }
    }
    __syncthreads();
    // 32 t x 256 ch = 2048 float4 slots; 8 per thread, coalesced per wave.
#pragma unroll
    for (int u = 0; u < 8; u++) {
        int slot = u * 256 + d;
        int row = slot >> 6, col = (slot & 63) << 2;
        *(float4*)&ob[(size_t)(s * CHUNK + row) * (2 * DOUT) + col] =
            *(float4*)&hbuf[row][col];
    }
}

// ---------------------------------------------------------------------------
extern "C" void kernel_launch(void* const* d_in, const int* in_sizes, int n_in,
                              void* d_out, int out_size, void* d_ws, size_t ws_size,
                              hipStream_t stream) {
    const float* x   = (const float*)d_in[0];
    // d_in[1] = lengths (unused by the reference computation)
    const float* Wf  = (const float*)d_in[2];
    const float* bfv = (const float*)d_in[3];
    const float* Wb  = (const float*)d_in[4];
    const float* bbv = (const float*)d_in[5];

    char* ws = (char*)d_ws;
    // Workspace layout (bytes):
    //   Xp    bf16  B*(L+2)*256          = 16,785,408   (offset 0; dead after GEMM)
    //   Wc    bf16  1536*768             =  2,359,296   (offset 16,785,408)
    //   bc    f32   1536                 =      6,144   (offset 19,144,704)
    //   gates fp16  B*L*1536             = 100,663,296  (offset 19,150,848, native layout)
    //   PW    f32x2 2*8*128*256          =  4,194,304   (offset 0 — reuses Xp)
    //   C0    f32   2*8*128*256          =  2,097,152   (offset 4,194,304 — reuses Xp)
    unsigned short* Xp    = (unsigned short*)(ws);
    unsigned short* Wc    = (unsigned short*)(ws + 16785408);
    float*          bc    = (float*)(ws + 19144704);
    _Float16*       gates = (_Float16*)(ws + 19150848);
    float2*         PW    = (float2*)(ws);              // reuse Xp region
    float*          C0    = (float*)(ws + 4194304);     // reuse Xp region
    float*          out   = (float*)d_out;

    prep_all<<<NXB + NWB, 256, 0, stream>>>(x, Xp, Wf, bfv, Wb, bbv, Wc, bc);
    gemm_gates<<<1536, 512, 0, stream>>>(Xp, Wc, bc, gates);
    scan_chunks<<<dim3(NCHUNK, B_, 2), 256, 0, stream>>>(gates, PW);
    scan_seq<<<16, 256, 0, stream>>>(PW, C0);
    scan_final<<<dim3(NCHUNK, B_, 2), 256, 0, stream>>>(gates, C0, out);
}

// Round 5
// 212.004 us; speedup vs baseline: 1.2009x; 1.0452x over previous
//
#include <hip/hip_runtime.h>
#include <hip/hip_bf16.h>
#include <hip/hip_fp16.h>

// Problem constants (match reference)
#define B_     8
#define L_     4096
#define DIN    256
#define DOUT   256
#define NGATE  1536   // 3*DOUT*2 dirs
#define KDIM   768    // 3*DIN (im2col window)
#define LP     (L_ + 2)
#define CHUNK  32
#define NCHUNK (L_ / CHUNK)

typedef short    short8  __attribute__((ext_vector_type(8)));
typedef __bf16   bf16x8  __attribute__((ext_vector_type(8)));
typedef float    floatx4 __attribute__((ext_vector_type(4)));
typedef _Float16 half4   __attribute__((ext_vector_type(4)));

__device__ __forceinline__ float fast_sigmoid(float x) {
    return __builtin_amdgcn_rcpf(1.f + __expf(-x));
}
__device__ __forceinline__ float fast_tanh(float x) {
    return 1.f - 2.f * __builtin_amdgcn_rcpf(1.f + __expf(2.f * x));
}
__device__ __forceinline__ unsigned short f2bf(float x) {
    unsigned u = __float_as_uint(x);
    u += 0x7FFF + ((u >> 16) & 1);   // RNE
    return (unsigned short)(u >> 16);
}
// Async global->LDS, 16B per lane. LDS dest = wave-uniform base + lane*16.
__device__ __forceinline__ void gload16(const unsigned short* g, unsigned short* l) {
    __builtin_amdgcn_global_load_lds((const __attribute__((address_space(1))) void*)g,
                                     (__attribute__((address_space(3))) void*)l,
                                     16, 0, 0);
}

// Gate column ordering (NEW in round 5) -------------------------------------
// 1536 columns = 2 dirs x 6 blocks(nblk%6=r) x 128 cols.
//   r in [0,4): fz-block, 64 channels (ch = r*64 + wcl*32 + (ni>>1)*16 + l16),
//               gate = (ni&1) ? z : f   (ni even = f, ni odd = z)
//   r in [4,6): o-block, ch = (r-4)*128 + c (c = col within block), gate = o
// This puts f and z of a channel in the SAME lane's accumulators at epilogue
// time, so the GEMM epilogue can compose the per-chunk affine map (P,W)
// in-register + 2 shfl_xor butterflies, eliminating the scan_chunks kernel.
//
// Storage layout within gates buffer (unchanged mechanics):
//   flat = ((bm*12 + nblk)*8 + wr*2+wcl)*4096 + (ni*4+mi)*256 + (quad*16+l16)*4 + rr
//   where t: bm=b*16+(t>>8), wr=(t>>6)&3, mi=(t>>4)&3, quad=(t>>2)&3, rr=t&3
__device__ __forceinline__ int toff_g(int b, int t) {
    return (b * 16 + (t >> 8)) * 393216 + ((t >> 6) & 3) * 8192
         + ((t >> 4) & 3) * 256 + ((t >> 2) & 3) * 64;
}
__device__ __forceinline__ int noff_f(int dir, int d) {
    int nblk = dir * 6 + (d >> 6);
    int wcl = (d >> 5) & 1, jb = (d >> 4) & 1, l16 = d & 15;
    return nblk * 32768 + wcl * 4096 + (jb * 2) * 1024 + l16 * 4;
}
__device__ __forceinline__ int noff_z(int dir, int d) {
    int nblk = dir * 6 + (d >> 6);
    int wcl = (d >> 5) & 1, jb = (d >> 4) & 1, l16 = d & 15;
    return nblk * 32768 + wcl * 4096 + (jb * 2 + 1) * 1024 + l16 * 4;
}
__device__ __forceinline__ int noff_o(int dir, int d) {
    int nblk = dir * 6 + 4 + (d >> 7);
    int c7 = d & 127;
    int wcl = c7 >> 6, ni = (c7 >> 4) & 3, l16 = d & 15;
    return nblk * 32768 + wcl * 4096 + ni * 1024 + l16 * 4;
}
// Decode new column index n (0..1535) -> row oc (0..767) within dir's W.
__device__ __forceinline__ int col_to_oc(int n, int* dir_out) {
    int nb = n >> 7, c = n & 127;
    int dir = nb / 6, r = nb % 6;
    int wcl = (c >> 6) & 1, ni = (c >> 4) & 3, l16 = c & 15;
    int oc;
    if (r < 4) oc = ((ni & 1) ? 512 : 0) + r * 64 + wcl * 32 + (ni >> 1) * 16 + l16;
    else       oc = 256 + (r - 4) * 128 + c;
    *dir_out = dir;
    return oc;
}

// ---------------------------------------------------------------------------
// prep_all: fused prep_x (blocks [0,NXB)) + prep_w (blocks [NXB,..)).
#define NXB ((B_ * LP * 64 + 255) / 256)
#define NWB ((NGATE * KDIM + 255) / 256)
__global__ void prep_all(const float* __restrict__ x, unsigned short* __restrict__ Xp,
                         const float* __restrict__ Wf, const float* __restrict__ bf_,
                         const float* __restrict__ Wb, const float* __restrict__ bb,
                         unsigned short* __restrict__ Wc, float* __restrict__ bc) {
    if (blockIdx.x < NXB) {
        int idx = blockIdx.x * 256 + threadIdx.x;
        int row = idx >> 6;
        if (row >= B_ * LP) return;
        int c4 = (idx & 63) << 2;
        int b = row / LP, r = row - b * LP;
        float4 v = make_float4(0.f, 0.f, 0.f, 0.f);
        if (r >= 1 && r <= L_) {
            v = *(const float4*)(x + ((size_t)(b * L_ + (r - 1))) * DIN + c4);
        }
        ushort4 o = make_ushort4(f2bf(v.x), f2bf(v.y), f2bf(v.z), f2bf(v.w));
        *(ushort4*)(Xp + (size_t)row * DIN + c4) = o;
    } else {
        int gid = (blockIdx.x - NXB) * 256 + threadIdx.x;
        if (gid < NGATE) {
            int dirb;
            int oc = col_to_oc(gid, &dirb);
            bc[gid] = dirb ? bb[oc] : bf_[oc];
        }
        if (gid >= NGATE * KDIM) return;
        int n = gid / KDIM, k = gid - n * KDIM;
        int s = k >> 8, ic = k & 255;
        int dirb;
        int oc = col_to_oc(n, &dirb);
        const float* W = dirb ? Wb : Wf;
        float v = W[(size_t)oc * KDIM + ic * 3 + s];
        Wc[(size_t)n * KDIM + k] = f2bf(v);
    }
}

// ---------------------------------------------------------------------------
// gemm_gates: 256x128 tile, 512 threads (8 waves), BK=64, 16x16x32 bf16 MFMA
// (round-0 proven 2-barrier structure; rounds 1-3 showed 8-phase ports
// regress on this short-K shape). NEW: fz-blocks' epilogue also composes the
// per-chunk affine maps (P,W) for the fo_pool scan (ordered quad-butterfly
// via shfl_xor) and writes PW directly -> scan_chunks kernel deleted.
__launch_bounds__(512)
__global__ void gemm_gates(const unsigned short* __restrict__ Xp,
                           const unsigned short* __restrict__ Wc,
                           const float* __restrict__ bc,
                           _Float16* __restrict__ gates,
                           float2* __restrict__ PWp) {
    __shared__ unsigned short As[256 * 64];   // 32 KB
    __shared__ unsigned short Bs[128 * 64];   // 16 KB
    const int tid  = threadIdx.x;
    const int lane = tid & 63, wave = tid >> 6;     // wave 0..7
    const int quad = lane >> 4, l16 = lane & 15;
    const int wr = wave >> 1, wcl = wave & 1;       // wr 0..3 (m), wcl 0..1 (n)

    int flat = blockIdx.x;                 // 0..1535
    int xcd  = flat & 7;
    int slot = flat >> 3;                  // 0..191
    int bm   = xcd * 16 + slot / 12;       // 0..127 m-tile (256 rows each)
    int nblk = slot % 12;
    const int b  = bm >> 4;
    const int t0 = (bm & 15) << 8;
    const int n0 = nblk << 7;
    const unsigned short* Ab = Xp + (size_t)b * LP * DIN;

    // Per-lane inverse-swizzle source mapping (constant across k-steps).
    int rowA[4], cgA[4], rowB[2], cgB[2];
#pragma unroll
    for (int j = 0; j < 4; j++) {
        int G = (wave * 4 + j) * 64 + lane;      // A granule 0..2047
        rowA[j] = G >> 3;
        cgA[j]  = ((G & 7) ^ (rowA[j] & 7)) * 8;
    }
#pragma unroll
    for (int j = 0; j < 2; j++) {
        int G = (wave * 2 + j) * 64 + lane;      // B granule 0..1023
        rowB[j] = G >> 3;
        cgB[j]  = ((G & 7) ^ (rowB[j] & 7)) * 8;
    }

    floatx4 acc[4][4];
#pragma unroll
    for (int i = 0; i < 4; i++)
#pragma unroll
        for (int j = 0; j < 4; j++) acc[i][j] = (floatx4)0.f;

    for (int k0 = 0; k0 < KDIM; k0 += 64) {
        const int sh = k0 >> 8;        // time shift 0..2
        const int c0 = k0 & 255;       // column offset within DIN
#pragma unroll
        for (int j = 0; j < 4; j++)
            gload16(Ab + (size_t)(t0 + rowA[j] + sh) * DIN + c0 + cgA[j],
                    &As[(wave * 4 + j) * 512]);
#pragma unroll
        for (int j = 0; j < 2; j++)
            gload16(Wc + (size_t)(n0 + rowB[j]) * KDIM + k0 + cgB[j],
                    &Bs[(wave * 2 + j) * 512]);
        __syncthreads();
#pragma unroll
        for (int kk = 0; kk < 2; kk++) {
            const int g0 = kk * 4 + quad;
            short8 af[4], bfr[4];
#pragma unroll
            for (int mi = 0; mi < 4; mi++) {
                int row = wr * 64 + mi * 16 + l16;
                af[mi] = *(const short8*)&As[row * 64 + ((g0 ^ (row & 7)) << 3)];
            }
#pragma unroll
            for (int ni = 0; ni < 4; ni++) {
                int row = wcl * 64 + ni * 16 + l16;
                bfr[ni] = *(const short8*)&Bs[row * 64 + ((g0 ^ (row & 7)) << 3)];
            }
#pragma unroll
            for (int mi = 0; mi < 4; mi++)
#pragma unroll
                for (int ni = 0; ni < 4; ni++)
                    acc[mi][ni] = __builtin_amdgcn_mfma_f32_16x16x32_bf16(
                        __builtin_bit_cast(bf16x8, af[mi]),
                        __builtin_bit_cast(bf16x8, bfr[ni]),
                        acc[mi][ni], 0, 0, 0);
        }
        __syncthreads();
    }

    // Epilogue --------------------------------------------------------------
    const int dir = nblk / 6;
    const int r6  = nblk % 6;
    _Float16* gb = gates + ((size_t)(bm * 12 + nblk) * 8 + wave) * 4096 + lane * 4;

    if (r6 >= 4) {
        // o-block: sigmoid, native-layout 8B stores.
#pragma unroll
        for (int ni = 0; ni < 4; ni++) {
            float bias = bc[n0 + wcl * 64 + ni * 16 + l16];
#pragma unroll
            for (int mi = 0; mi < 4; mi++) {
                half4 hv;
#pragma unroll
                for (int rr = 0; rr < 4; rr++)
                    hv[rr] = (_Float16)fast_sigmoid(acc[mi][ni][rr] + bias);
                *(half4*)(gb + (ni * 4 + mi) * 256) = hv;
            }
        }
    } else {
        // fz-block: activations + store + per-chunk affine map (P,W).
        const bool fwd = (dir == 0);
#pragma unroll
        for (int j = 0; j < 2; j++) {
            float biasF = bc[n0 + wcl * 64 + (2 * j) * 16 + l16];
            float biasZ = bc[n0 + wcl * 64 + (2 * j + 1) * 16 + l16];
            float Pm[4], Wm[4];
#pragma unroll
            for (int mi = 0; mi < 4; mi++) {
                half4 hf, hz;
                float P = 1.f, W = 0.f;
                if (fwd) {
#pragma unroll
                    for (int rr = 0; rr < 4; rr++) {
                        float f = fast_sigmoid(acc[mi][2 * j][rr] + biasF);
                        float z = fast_tanh(acc[mi][2 * j + 1][rr] + biasZ);
                        hf[rr] = (_Float16)f; hz[rr] = (_Float16)z;
                        W = f * W + (1.f - f) * z; P *= f;
                    }
                } else {
#pragma unroll
                    for (int rr = 3; rr >= 0; rr--) {
                        float f = fast_sigmoid(acc[mi][2 * j][rr] + biasF);
                        float z = fast_tanh(acc[mi][2 * j + 1][rr] + biasZ);
                        hf[rr] = (_Float16)f; hz[rr] = (_Float16)z;
                        W = f * W + (1.f - f) * z; P *= f;
                    }
                }
                *(half4*)(gb + ((2 * j) * 4 + mi) * 256) = hf;
                *(half4*)(gb + ((2 * j + 1) * 4 + mi) * 256) = hz;
                // Ordered butterfly across quads (traversal order).
                // comp(first A, then B) = (PB*PA, PB*WA + WB)
#pragma unroll
                for (int st = 0; st < 2; st++) {
                    int msk = 16 << st;
                    float Po = __shfl_xor(P, msk);
                    float Wo = __shfl_xor(W, msk);
                    bool later = (((lane & msk) != 0) == fwd);
                    float nP = later ? (P * Po) : (Po * P);
                    float nW = later ? (P * Wo + W) : (Po * W + Wo);
                    P = nP; W = nW;
                }
                Pm[mi] = P; Wm[mi] = W;
            }
            // Chunk maps: half0 = mi{0,1} (t 0..31 of wave window), half1 = mi{2,3}.
            if (quad < 2) {
                int half = quad;
                int mlo = half * 2, mhi = half * 2 + 1;
                float Pc, Wc2;
                if (fwd) { Pc = Pm[mhi] * Pm[mlo]; Wc2 = Pm[mhi] * Wm[mlo] + Wm[mhi]; }
                else     { Pc = Pm[mlo] * Pm[mhi]; Wc2 = Pm[mlo] * Wm[mhi] + Wm[mlo]; }
                int s  = (bm & 15) * 8 + wr * 2 + half;
                int ch = r6 * 64 + wcl * 32 + j * 16 + l16;
                PWp[(((size_t)(dir * 8 + b)) * NCHUNK + s) * 256 + ch] =
                    make_float2(Pc, Wc2);
            }
        }
    }
}

// ---------------------------------------------------------------------------
// scan_seq (phase B): sequential scan over NCHUNK=128 chunks.
__global__ void scan_seq(const float2* __restrict__ PW, float* __restrict__ C0) {
    const int c = threadIdx.x;
    const int dir = blockIdx.x >> 3, b = blockIdx.x & 7;
    const size_t base = ((size_t)(dir * 8 + b)) * NCHUNK * 256 + c;
    float cc = 0.f;
    if (dir == 0) {
#pragma unroll 16
        for (int s = 0; s < NCHUNK; s++) {
            float2 pw = PW[base + (size_t)s * 256];
            C0[base + (size_t)s * 256] = cc;
            cc = pw.x * cc + pw.y;
        }
    } else {
#pragma unroll 16
        for (int s = NCHUNK - 1; s >= 0; s--) {
            float2 pw = PW[base + (size_t)s * 256];
            C0[base + (size_t)s * 256] = cc;
            cc = pw.x * cc + pw.y;
        }
    }
}

// ---------------------------------------------------------------------------
// scan_final (phase C): thread = one channel, block = one (chunk,b,dir).
// Replays the chunk from C0 using the fp16 gates (new column order); h goes
// through a 32KB LDS tile (single barrier) then 8 coalesced float4 stores.
__global__ void scan_final(const _Float16* __restrict__ gates,
                           const float* __restrict__ C0,
                           float* __restrict__ out) {
    __shared__ float hbuf[CHUNK][256];   // 32 KB
    const int d = threadIdx.x;
    const int s = blockIdx.x, b = blockIdx.y, dir = blockIdx.z;
    const int onf = noff_f(dir, d);
    const int ono = noff_o(dir, d);
    const int onz = noff_z(dir, d);
    float c = C0[(((size_t)(dir * 8 + b)) * NCHUNK + s) * 256 + d];
    float* ob = out + (size_t)(b * L_) * (2 * DOUT) + dir * DOUT;
    float* lasth = out + (size_t)B_ * L_ * (2 * DOUT);
    float* lastc = lasth + B_ * (2 * DOUT);

#pragma unroll
    for (int gg = 0; gg < 8; gg++) {
        int gi = (dir == 0) ? gg : 7 - gg;
        int t = s * CHUNK + gi * 4;
        int ot = toff_g(b, t);
        half4 f4 = *(const half4*)(gates + ot + onf);
        half4 o4 = *(const half4*)(gates + ot + ono);
        half4 z4 = *(const half4*)(gates + ot + onz);
        if (dir == 0) {
#pragma unroll
            for (int u = 0; u < 4; u++) {
                float f = (float)f4[u], z = (float)z4[u];
                c = f * c + (1.f - f) * z;
                float h = c * (float)o4[u];
                hbuf[gi * 4 + u][d] = h;
                if (s == NCHUNK - 1 && gi == 7 && u == 3) {
                    lasth[b * 2 * DOUT + d] = h;
                    lastc[b * 2 * DOUT + d] = c;
                }
            }
        } else {
#pragma unroll
            for (int u = 3; u >= 0; u--) {
                float f = (float)f4[u], z = (float)z4[u];
                c = f * c + (1.f - f) * z;
                float h = c * (float)o4[u];
                hbuf[gi * 4 + u][d] = h;
                if (u == 3 && s == NCHUNK - 1 && gi == 7) {
                    lasth[b * 2 * DOUT + DOUT + d] = h;
                    lastc[b * 2 * DOUT + DOUT + d] = c;
                }
            }
        }
    }
    __syncthreads();
    // 32 t x 256 ch = 2048 float4 slots; 8 per thread, coalesced per wave.
#pragma unroll
    for (int u = 0; u < 8; u++) {
        int slot = u * 256 + d;
        int row = slot >> 6, col = (slot & 63) << 2;
        *(float4*)&ob[(size_t)(s * CHUNK + row) * (2 * DOUT) + col] =
            *(float4*)&hbuf[row][col];
    }
}

// ---------------------------------------------------------------------------
extern "C" void kernel_launch(void* const* d_in, const int* in_sizes, int n_in,
                              void* d_out, int out_size, void* d_ws, size_t ws_size,
                              hipStream_t stream) {
    const float* x   = (const float*)d_in[0];
    // d_in[1] = lengths (unused by the reference computation)
    const float* Wf  = (const float*)d_in[2];
    const float* bfv = (const float*)d_in[3];
    const float* Wb  = (const float*)d_in[4];
    const float* bbv = (const float*)d_in[5];

    char* ws = (char*)d_ws;
    // Workspace layout (bytes):
    //   Xp    bf16  B*(L+2)*256          = 16,785,408   (offset 0; dead after GEMM)
    //   Wc    bf16  1536*768             =  2,359,296   (offset 16,785,408)
    //   bc    f32   1536                 =      6,144   (offset 19,144,704)
    //   gates fp16  B*L*1536             = 100,663,296  (offset 19,150,848, new col order)
    //   C0    f32   2*8*128*256          =  2,097,152   (offset 4,194,304 — reuses Xp,
    //                                                    written after GEMM completes)
    //   PW    f32x2 2*8*128*256          =  4,194,304   -> lives in d_out[0..4MB]
    //         (GEMM epilogue writes it; dead before scan_final overwrites out)
    unsigned short* Xp    = (unsigned short*)(ws);
    unsigned short* Wc    = (unsigned short*)(ws + 16785408);
    float*          bc    = (float*)(ws + 19144704);
    _Float16*       gates = (_Float16*)(ws + 19150848);
    float*          C0    = (float*)(ws + 4194304);     // reuse Xp region
    float2*         PW    = (float2*)d_out;             // scratch in output buffer
    float*          out   = (float*)d_out;

    prep_all<<<NXB + NWB, 256, 0, stream>>>(x, Xp, Wf, bfv, Wb, bbv, Wc, bc);
    gemm_gates<<<1536, 512, 0, stream>>>(Xp, Wc, bc, gates, PW);
    scan_seq<<<16, 256, 0, stream>>>(PW, C0);
    scan_final<<<dim3(NCHUNK, B_, 2), 256, 0, stream>>>(gates, C0, out);
}

// Round 7
// 209.201 us; speedup vs baseline: 1.2170x; 1.0134x over previous
//
#include <hip/hip_runtime.h>
#include <hip/hip_bf16.h>
#include <hip/hip_fp16.h>

// Problem constants (match reference)
#define B_     8
#define L_     4096
#define DIN    256
#define DOUT   256
#define NGATE  1536   // 3*DOUT*2 dirs
#define KDIM   768    // 3*DIN (im2col window)
#define LP     (L_ + 2)
#define CHUNK  32
#define NCHUNK (L_ / CHUNK)

typedef short    short8  __attribute__((ext_vector_type(8)));
typedef __bf16   bf16x8  __attribute__((ext_vector_type(8)));
typedef float    floatx4 __attribute__((ext_vector_type(4)));
typedef _Float16 half4   __attribute__((ext_vector_type(4)));
typedef _Float16 half8   __attribute__((ext_vector_type(8)));

__device__ __forceinline__ float fast_sigmoid(float x) {
    return __builtin_amdgcn_rcpf(1.f + __expf(-x));
}
__device__ __forceinline__ float fast_tanh(float x) {
    return 1.f - 2.f * __builtin_amdgcn_rcpf(1.f + __expf(2.f * x));
}
__device__ __forceinline__ unsigned short f2bf(float x) {
    unsigned u = __float_as_uint(x);
    u += 0x7FFF + ((u >> 16) & 1);   // RNE
    return (unsigned short)(u >> 16);
}
// Async global->LDS, 16B per lane. LDS dest = wave-uniform base + lane*16.
__device__ __forceinline__ void gload16(const unsigned short* g, unsigned short* l) {
    __builtin_amdgcn_global_load_lds((const __attribute__((address_space(1))) void*)g,
                                     (__attribute__((address_space(3))) void*)l,
                                     16, 0, 0);
}

// Gate column ordering (round 5) --------------------------------------------
// 1536 columns = 2 dirs x 6 blocks(nblk%6=r) x 128 cols.
//   r in [0,4): fz-block, 64 channels (ch = r*64 + wcl*32 + (ni>>1)*16 + l16),
//               gate = (ni&1) ? z : f   (ni even = f, ni odd = z)
//   r in [4,6): o-block, ch = (r-4)*128 + c, gate = o
// Storage: flat = ((bm*12+nblk)*8 + wr*2+wcl)*4096 + (ni*4+mi)*256
//                 + (quad*16+l16)*4 + rr
__device__ __forceinline__ int toff_g(int b, int t) {
    return (b * 16 + (t >> 8)) * 393216 + ((t >> 6) & 3) * 8192
         + ((t >> 4) & 3) * 256 + ((t >> 2) & 3) * 64;
}
__device__ __forceinline__ int noff_f(int dir, int d) {
    int nblk = dir * 6 + (d >> 6);
    int wcl = (d >> 5) & 1, jb = (d >> 4) & 1, l16 = d & 15;
    return nblk * 32768 + wcl * 4096 + (jb * 2) * 1024 + l16 * 4;
}
__device__ __forceinline__ int noff_z(int dir, int d) {
    int nblk = dir * 6 + (d >> 6);
    int wcl = (d >> 5) & 1, jb = (d >> 4) & 1, l16 = d & 15;
    return nblk * 32768 + wcl * 4096 + (jb * 2 + 1) * 1024 + l16 * 4;
}
__device__ __forceinline__ int noff_o(int dir, int d) {
    int nblk = dir * 6 + 4 + (d >> 7);
    int c7 = d & 127;
    int wcl = c7 >> 6, ni = (c7 >> 4) & 3, l16 = d & 15;
    return nblk * 32768 + wcl * 4096 + ni * 1024 + l16 * 4;
}
// Decode new column index n (0..1535) -> row oc (0..767) within dir's W.
__device__ __forceinline__ int col_to_oc(int n, int* dir_out) {
    int nb = n >> 7, c = n & 127;
    int dir = nb / 6, r = nb % 6;
    int wcl = (c >> 6) & 1, ni = (c >> 4) & 3, l16 = c & 15;
    int oc;
    if (r < 4) oc = ((ni & 1) ? 512 : 0) + r * 64 + wcl * 32 + (ni >> 1) * 16 + l16;
    else       oc = 256 + (r - 4) * 128 + c;
    *dir_out = dir;
    return oc;
}

// ---------------------------------------------------------------------------
// prep_all: fused prep_x (blocks [0,NXB)) + prep_w (blocks [NXB,..)).
#define NXB ((B_ * LP * 64 + 255) / 256)
#define NWB ((NGATE * KDIM + 255) / 256)
__global__ void prep_all(const float* __restrict__ x, unsigned short* __restrict__ Xp,
                         const float* __restrict__ Wf, const float* __restrict__ bf_,
                         const float* __restrict__ Wb, const float* __restrict__ bb,
                         unsigned short* __restrict__ Wc, float* __restrict__ bc) {
    if (blockIdx.x < NXB) {
        int idx = blockIdx.x * 256 + threadIdx.x;
        int row = idx >> 6;
        if (row >= B_ * LP) return;
        int c4 = (idx & 63) << 2;
        int b = row / LP, r = row - b * LP;
        float4 v = make_float4(0.f, 0.f, 0.f, 0.f);
        if (r >= 1 && r <= L_) {
            v = *(const float4*)(x + ((size_t)(b * L_ + (r - 1))) * DIN + c4);
        }
        ushort4 o = make_ushort4(f2bf(v.x), f2bf(v.y), f2bf(v.z), f2bf(v.w));
        *(ushort4*)(Xp + (size_t)row * DIN + c4) = o;
    } else {
        int gid = (blockIdx.x - NXB) * 256 + threadIdx.x;
        if (gid < NGATE) {
            int dirb;
            int oc = col_to_oc(gid, &dirb);
            bc[gid] = dirb ? bb[oc] : bf_[oc];
        }
        if (gid >= NGATE * KDIM) return;
        int n = gid / KDIM, k = gid - n * KDIM;
        int s = k >> 8, ic = k & 255;
        int dirb;
        int oc = col_to_oc(n, &dirb);
        const float* W = dirb ? Wb : Wf;
        float v = W[(size_t)oc * KDIM + ic * 3 + s];
        Wc[(size_t)n * KDIM + k] = f2bf(v);
    }
}

// ---------------------------------------------------------------------------
// gemm_gates: 256x128 tile, 512 threads (8 waves), BK=64, 16x16x32 bf16 MFMA
// (round-0 proven 2-barrier structure at its structural ceiling; rounds 1-3
// showed 8-phase ports regress on this short-K shape). Epilogue: activations
// + native-layout stores + per-chunk affine map (P,W) via ordered
// quad-butterfly (round 5) -> scan_chunks kernel eliminated.
__launch_bounds__(512)
__global__ void gemm_gates(const unsigned short* __restrict__ Xp,
                           const unsigned short* __restrict__ Wc,
                           const float* __restrict__ bc,
                           _Float16* __restrict__ gates,
                           float2* __restrict__ PWp) {
    __shared__ unsigned short As[256 * 64];   // 32 KB
    __shared__ unsigned short Bs[128 * 64];   // 16 KB
    const int tid  = threadIdx.x;
    const int lane = tid & 63, wave = tid >> 6;     // wave 0..7
    const int quad = lane >> 4, l16 = lane & 15;
    const int wr = wave >> 1, wcl = wave & 1;       // wr 0..3 (m), wcl 0..1 (n)

    int flat = blockIdx.x;                 // 0..1535
    int xcd  = flat & 7;
    int slot = flat >> 3;                  // 0..191
    int bm   = xcd * 16 + slot / 12;       // 0..127 m-tile (256 rows each)
    int nblk = slot % 12;
    const int b  = bm >> 4;
    const int t0 = (bm & 15) << 8;
    const int n0 = nblk << 7;
    const unsigned short* Ab = Xp + (size_t)b * LP * DIN;

    // Per-lane inverse-swizzle source mapping (constant across k-steps).
    int rowA[4], cgA[4], rowB[2], cgB[2];
#pragma unroll
    for (int j = 0; j < 4; j++) {
        int G = (wave * 4 + j) * 64 + lane;      // A granule 0..2047
        rowA[j] = G >> 3;
        cgA[j]  = ((G & 7) ^ (rowA[j] & 7)) * 8;
    }
#pragma unroll
    for (int j = 0; j < 2; j++) {
        int G = (wave * 2 + j) * 64 + lane;      // B granule 0..1023
        rowB[j] = G >> 3;
        cgB[j]  = ((G & 7) ^ (rowB[j] & 7)) * 8;
    }

    floatx4 acc[4][4];
#pragma unroll
    for (int i = 0; i < 4; i++)
#pragma unroll
        for (int j = 0; j < 4; j++) acc[i][j] = (floatx4)0.f;

    for (int k0 = 0; k0 < KDIM; k0 += 64) {
        const int sh = k0 >> 8;        // time shift 0..2
        const int c0 = k0 & 255;       // column offset within DIN
#pragma unroll
        for (int j = 0; j < 4; j++)
            gload16(Ab + (size_t)(t0 + rowA[j] + sh) * DIN + c0 + cgA[j],
                    &As[(wave * 4 + j) * 512]);
#pragma unroll
        for (int j = 0; j < 2; j++)
            gload16(Wc + (size_t)(n0 + rowB[j]) * KDIM + k0 + cgB[j],
                    &Bs[(wave * 2 + j) * 512]);
        __syncthreads();
#pragma unroll
        for (int kk = 0; kk < 2; kk++) {
            const int g0 = kk * 4 + quad;
            short8 af[4], bfr[4];
#pragma unroll
            for (int mi = 0; mi < 4; mi++) {
                int row = wr * 64 + mi * 16 + l16;
                af[mi] = *(const short8*)&As[row * 64 + ((g0 ^ (row & 7)) << 3)];
            }
#pragma unroll
            for (int ni = 0; ni < 4; ni++) {
                int row = wcl * 64 + ni * 16 + l16;
                bfr[ni] = *(const short8*)&Bs[row * 64 + ((g0 ^ (row & 7)) << 3)];
            }
#pragma unroll
            for (int mi = 0; mi < 4; mi++)
#pragma unroll
                for (int ni = 0; ni < 4; ni++)
                    acc[mi][ni] = __builtin_amdgcn_mfma_f32_16x16x32_bf16(
                        __builtin_bit_cast(bf16x8, af[mi]),
                        __builtin_bit_cast(bf16x8, bfr[ni]),
                        acc[mi][ni], 0, 0, 0);
        }
        __syncthreads();
    }

    // Epilogue --------------------------------------------------------------
    const int dir = nblk / 6;
    const int r6  = nblk % 6;
    _Float16* gb = gates + ((size_t)(bm * 12 + nblk) * 8 + wave) * 4096 + lane * 4;

    if (r6 >= 4) {
        // o-block: sigmoid, native-layout 8B stores.
#pragma unroll
        for (int ni = 0; ni < 4; ni++) {
            float bias = bc[n0 + wcl * 64 + ni * 16 + l16];
#pragma unroll
            for (int mi = 0; mi < 4; mi++) {
                half4 hv;
#pragma unroll
                for (int rr = 0; rr < 4; rr++)
                    hv[rr] = (_Float16)fast_sigmoid(acc[mi][ni][rr] + bias);
                *(half4*)(gb + (ni * 4 + mi) * 256) = hv;
            }
        }
    } else {
        // fz-block: activations + store + per-chunk affine map (P,W).
        const bool fwd = (dir == 0);
#pragma unroll
        for (int j = 0; j < 2; j++) {
            float biasF = bc[n0 + wcl * 64 + (2 * j) * 16 + l16];
            float biasZ = bc[n0 + wcl * 64 + (2 * j + 1) * 16 + l16];
            float Pm[4], Wm[4];
#pragma unroll
            for (int mi = 0; mi < 4; mi++) {
                half4 hf, hz;
                float P = 1.f, W = 0.f;
                if (fwd) {
#pragma unroll
                    for (int rr = 0; rr < 4; rr++) {
                        float f = fast_sigmoid(acc[mi][2 * j][rr] + biasF);
                        float z = fast_tanh(acc[mi][2 * j + 1][rr] + biasZ);
                        hf[rr] = (_Float16)f; hz[rr] = (_Float16)z;
                        W = f * W + (1.f - f) * z; P *= f;
                    }
                } else {
#pragma unroll
                    for (int rr = 3; rr >= 0; rr--) {
                        float f = fast_sigmoid(acc[mi][2 * j][rr] + biasF);
                        float z = fast_tanh(acc[mi][2 * j + 1][rr] + biasZ);
                        hf[rr] = (_Float16)f; hz[rr] = (_Float16)z;
                        W = f * W + (1.f - f) * z; P *= f;
                    }
                }
                *(half4*)(gb + ((2 * j) * 4 + mi) * 256) = hf;
                *(half4*)(gb + ((2 * j + 1) * 4 + mi) * 256) = hz;
                // Ordered butterfly across quads (traversal order).
                // comp(first A, then B) = (PB*PA, PB*WA + WB)
#pragma unroll
                for (int st = 0; st < 2; st++) {
                    int msk = 16 << st;
                    float Po = __shfl_xor(P, msk);
                    float Wo = __shfl_xor(W, msk);
                    bool later = (((lane & msk) != 0) == fwd);
                    float nP = later ? (P * Po) : (Po * P);
                    float nW = later ? (P * Wo + W) : (Po * W + Wo);
                    P = nP; W = nW;
                }
                Pm[mi] = P; Wm[mi] = W;
            }
            // Chunk maps: half0 = mi{0,1} (t 0..31 of wave window), half1 = mi{2,3}.
            if (quad < 2) {
                int half = quad;
                int mlo = half * 2, mhi = half * 2 + 1;
                float Pc, Wc2;
                if (fwd) { Pc = Pm[mhi] * Pm[mlo]; Wc2 = Pm[mhi] * Wm[mlo] + Wm[mhi]; }
                else     { Pc = Pm[mlo] * Pm[mhi]; Wc2 = Pm[mlo] * Wm[mhi] + Wm[mlo]; }
                int s  = (bm & 15) * 8 + wr * 2 + half;
                int ch = r6 * 64 + wcl * 32 + j * 16 + l16;
                PWp[(((size_t)(dir * 8 + b)) * NCHUNK + s) * 256 + ch] =
                    make_float2(Pc, Wc2);
            }
        }
    }
}

// ---------------------------------------------------------------------------
// scan_seq (phase B): sequential scan over NCHUNK=128 chunks.
__global__ void scan_seq(const float2* __restrict__ PW, float* __restrict__ C0) {
    const int c = threadIdx.x;
    const int dir = blockIdx.x >> 3, b = blockIdx.x & 7;
    const size_t base = ((size_t)(dir * 8 + b)) * NCHUNK * 256 + c;
    float cc = 0.f;
    if (dir == 0) {
#pragma unroll 16
        for (int s = 0; s < NCHUNK; s++) {
            float2 pw = PW[base + (size_t)s * 256];
            C0[base + (size_t)s * 256] = cc;
            cc = pw.x * cc + pw.y;
        }
    } else {
#pragma unroll 16
        for (int s = NCHUNK - 1; s >= 0; s--) {
            float2 pw = PW[base + (size_t)s * 256];
            C0[base + (size_t)s * 256] = cc;
            cc = pw.x * cc + pw.y;
        }
    }
}

// ---------------------------------------------------------------------------
// scan_final (phase C), round-7: 128 threads/block, each owns TWO adjacent
// channels (d0 = 2*tid, d0+1; same 16-ch gate group since d0 is even). All
// gate loads become 16B (half8 = both channels' 4 t), C0 is read as float2,
// and h is stored directly as float2 (64 lanes x 8B = 512B contiguous per
// t-row) — no LDS tile, no barrier.
__global__ void scan_final(const _Float16* __restrict__ gates,
                           const float* __restrict__ C0,
                           float* __restrict__ out) {
    const int d0 = threadIdx.x * 2;
    const int s = blockIdx.x, b = blockIdx.y, dir = blockIdx.z;
    const int onf = noff_f(dir, d0);
    const int ono = noff_o(dir, d0);
    const int onz = noff_z(dir, d0);
    float2 c2 = *(const float2*)&C0[(((size_t)(dir * 8 + b)) * NCHUNK + s) * 256 + d0];
    float ca = c2.x, cb = c2.y;
    float* ob = out + (size_t)(b * L_) * (2 * DOUT) + dir * DOUT;
    float* lasth = out + (size_t)B_ * L_ * (2 * DOUT);
    float* lastc = lasth + B_ * (2 * DOUT);

#pragma unroll
    for (int gg = 0; gg < 8; gg++) {
        int gi = (dir == 0) ? gg : 7 - gg;
        int t = s * CHUNK + gi * 4;
        int ot = toff_g(b, t);
        half8 f8 = *(const half8*)(gates + ot + onf);
        half8 o8 = *(const half8*)(gates + ot + ono);
        half8 z8 = *(const half8*)(gates + ot + onz);
        if (dir == 0) {
#pragma unroll
            for (int u = 0; u < 4; u++) {
                float fa = (float)f8[u], za = (float)z8[u];
                float fb = (float)f8[4 + u], zb = (float)z8[4 + u];
                ca = fa * ca + (1.f - fa) * za;
                cb = fb * cb + (1.f - fb) * zb;
                float2 h = make_float2(ca * (float)o8[u], cb * (float)o8[4 + u]);
                *(float2*)&ob[(size_t)(t + u) * (2 * DOUT) + d0] = h;
                if (s == NCHUNK - 1 && gi == 7 && u == 3) {
                    *(float2*)&lasth[b * 2 * DOUT + d0] = h;
                    *(float2*)&lastc[b * 2 * DOUT + d0] = make_float2(ca, cb);
                }
            }
        } else {
#pragma unroll
            for (int u = 3; u >= 0; u--) {
                float fa = (float)f8[u], za = (float)z8[u];
                float fb = (float)f8[4 + u], zb = (float)z8[4 + u];
                ca = fa * ca + (1.f - fa) * za;
                cb = fb * cb + (1.f - fb) * zb;
                float2 h = make_float2(ca * (float)o8[u], cb * (float)o8[4 + u]);
                *(float2*)&ob[(size_t)(t + u) * (2 * DOUT) + d0] = h;
                if (u == 3 && s == NCHUNK - 1 && gi == 7) {
                    *(float2*)&lasth[b * 2 * DOUT + DOUT + d0] = h;
                    *(float2*)&lastc[b * 2 * DOUT + DOUT + d0] = make_float2(ca, cb);
                }
            }
        }
    }
}

// ---------------------------------------------------------------------------
extern "C" void kernel_launch(void* const* d_in, const int* in_sizes, int n_in,
                              void* d_out, int out_size, void* d_ws, size_t ws_size,
                              hipStream_t stream) {
    const float* x   = (const float*)d_in[0];
    // d_in[1] = lengths (unused by the reference computation)
    const float* Wf  = (const float*)d_in[2];
    const float* bfv = (const float*)d_in[3];
    const float* Wb  = (const float*)d_in[4];
    const float* bbv = (const float*)d_in[5];

    char* ws = (char*)d_ws;
    // Workspace layout (bytes):
    //   Xp    bf16  B*(L+2)*256          = 16,785,408   (offset 0; dead after GEMM)
    //   Wc    bf16  1536*768             =  2,359,296   (offset 16,785,408)
    //   bc    f32   1536                 =      6,144   (offset 19,144,704)
    //   gates fp16  B*L*1536             = 100,663,296  (offset 19,150,848)
    //   C0    f32   2*8*128*256          =  2,097,152   (offset 4,194,304 — reuses Xp,
    //                                                    written after GEMM completes)
    //   PW    f32x2 2*8*128*256          =  4,194,304   -> d_out[0..4MB] scratch
    //         (GEMM epilogue writes it; dead before scan_final overwrites out)
    unsigned short* Xp    = (unsigned short*)(ws);
    unsigned short* Wc    = (unsigned short*)(ws + 16785408);
    float*          bc    = (float*)(ws + 19144704);
    _Float16*       gates = (_Float16*)(ws + 19150848);
    float*          C0    = (float*)(ws + 4194304);     // reuse Xp region
    float2*         PW    = (float2*)d_out;             // scratch in output buffer
    float*          out   = (float*)d_out;

    prep_all<<<NXB + NWB, 256, 0, stream>>>(x, Xp, Wf, bfv, Wb, bbv, Wc, bc);
    gemm_gates<<<1536, 512, 0, stream>>>(Xp, Wc, bc, gates, PW);
    scan_seq<<<16, 256, 0, stream>>>(PW, C0);
    scan_final<<<dim3(NCHUNK, B_, 2), 128, 0, stream>>>(gates, C0, out);
}